// Round 1
// baseline (52194.446 us; speedup 1.0000x reference)
//
#include <hip/hip_runtime.h>

#define NB 256       // batch
#define H 512        // hidden
#define OBS 128      // obs dim
#define LSTEPS 512   // timesteps
#define NLAYER 4

// Fused GEMM + LIF:  acc[n,h] = sum_k S[n,k]*W[h,k];  then LIF update.
// S: [NB x K], W: [H x K] row-major, b: [H], mem: [NB x H] in/out, spk_out: [NB x H]
__global__ __launch_bounds__(256) void gemm_lif_kernel(
    const float* __restrict__ S, int K,
    const float* __restrict__ W,
    const float* __restrict__ b,
    float* __restrict__ mem,
    float* __restrict__ spk_out)
{
    __shared__ float St[32][33];   // +1 pad: compute reads St[row][kk] -> bank (row+kk)%32
    __shared__ float Wt[32][33];

    const int tid = threadIdx.x;
    const int tx = tid & 15;       // h sub-tile
    const int ty = tid >> 4;       // n sub-tile
    const int h0 = blockIdx.x * 32;
    const int n0 = blockIdx.y * 32;

    const int lrow = tid >> 3;         // 0..31
    const int lcol = (tid & 7) * 4;    // 0,4,...,28

    float acc00 = 0.f, acc01 = 0.f, acc10 = 0.f, acc11 = 0.f;

    for (int kc = 0; kc < K; kc += 32) {
        float4 sv = *(const float4*)(S + (size_t)(n0 + lrow) * K + kc + lcol);
        float4 wv = *(const float4*)(W + (size_t)(h0 + lrow) * K + kc + lcol);
        St[lrow][lcol + 0] = sv.x; St[lrow][lcol + 1] = sv.y;
        St[lrow][lcol + 2] = sv.z; St[lrow][lcol + 3] = sv.w;
        Wt[lrow][lcol + 0] = wv.x; Wt[lrow][lcol + 1] = wv.y;
        Wt[lrow][lcol + 2] = wv.z; Wt[lrow][lcol + 3] = wv.w;
        __syncthreads();
        #pragma unroll
        for (int kk = 0; kk < 32; ++kk) {
            float a0 = St[ty * 2 + 0][kk];
            float a1 = St[ty * 2 + 1][kk];
            float b0 = Wt[tx * 2 + 0][kk];
            float b1 = Wt[tx * 2 + 1][kk];
            acc00 += a0 * b0; acc01 += a0 * b1;
            acc10 += a1 * b0; acc11 += a1 * b1;
        }
        __syncthreads();
    }

    const float BETA = 0.9f, TH = 1.0f;
    float accs[2][2] = {{acc00, acc01}, {acc10, acc11}};
    #pragma unroll
    for (int i = 0; i < 2; ++i) {
        #pragma unroll
        for (int j = 0; j < 2; ++j) {
            int n = n0 + ty * 2 + i;
            int h = h0 + tx * 2 + j;
            size_t idx = (size_t)n * H + h;
            float mp = mem[idx];
            float reset = (mp > TH) ? 1.0f : 0.0f;
            float m = BETA * mp + (accs[i][j] + b[h]) - reset * TH;
            mem[idx] = m;
            spk_out[idx] = ((m - TH) > 0.0f) ? 1.0f : 0.0f;
        }
    }
}

extern "C" void kernel_launch(void* const* d_in, const int* in_sizes, int n_in,
                              void* d_out, int out_size, void* d_ws, size_t ws_size,
                              hipStream_t stream) {
    const float* x     = (const float*)d_in[0];  // [512,256,128]
    const float* mem0  = (const float*)d_in[1];  // [5,256,512]
    const float* enc_W = (const float*)d_in[2];  // [512,128]
    const float* enc_b = (const float*)d_in[3];  // [512]
    const float* fc_W  = (const float*)d_in[4];  // [4,512,512]
    const float* fc_b  = (const float*)d_in[5];  // [4,512]
    float* out = (float*)d_out;                  // [512,256,512] spikes + [5,256,512] mem

    const size_t PLANE = (size_t)NB * H;         // 131072
    float* mem  = (float*)d_ws;                  // 5 planes
    float* spkA = mem + 5 * PLANE;
    float* spkB = spkA + PLANE;

    // fresh state every call (harness does not re-poison between replays)
    hipMemcpyAsync(mem, mem0, 5 * PLANE * sizeof(float), hipMemcpyDeviceToDevice, stream);

    dim3 grid(H / 32, NB / 32);   // 16 x 8 = 128 blocks
    dim3 block(256);

    for (int t = 0; t < LSTEPS; ++t) {
        const float* xt = x + (size_t)t * NB * OBS;
        // encoder
        gemm_lif_kernel<<<grid, block, 0, stream>>>(xt, OBS, enc_W, enc_b, mem, spkA);
        // fc layers 0..2
        gemm_lif_kernel<<<grid, block, 0, stream>>>(spkA, H, fc_W + 0 * (size_t)H * H, fc_b + 0 * H, mem + 1 * PLANE, spkB);
        gemm_lif_kernel<<<grid, block, 0, stream>>>(spkB, H, fc_W + 1 * (size_t)H * H, fc_b + 1 * H, mem + 2 * PLANE, spkA);
        gemm_lif_kernel<<<grid, block, 0, stream>>>(spkA, H, fc_W + 2 * (size_t)H * H, fc_b + 2 * H, mem + 3 * PLANE, spkB);
        // fc layer 3: spikes go straight to d_out
        gemm_lif_kernel<<<grid, block, 0, stream>>>(spkB, H, fc_W + 3 * (size_t)H * H, fc_b + 3 * H, mem + 4 * PLANE, out + (size_t)t * PLANE);
    }

    // mem_final
    hipMemcpyAsync(out + (size_t)LSTEPS * PLANE, mem, 5 * PLANE * sizeof(float),
                   hipMemcpyDeviceToDevice, stream);
}

// Round 2
// 45255.627 us; speedup vs baseline: 1.1533x; 1.1533x over previous
//
#include <hip/hip_runtime.h>

#define H 512
#define NB 256
#define OBS 128
#define LSTEPS 512
#define NPHASE (LSTEPS + 4)   // 516 wavefront phases
#define NWG 256

// ---------------- weight pre-transpose (once per call) ----------------
// fc_Wt[l][k][h] = fc_W[l][h][k];  enc_Wt[k][h] = enc_W[h][k]
__global__ __launch_bounds__(256) void prep_weights(const float* __restrict__ enc_W,
                                                    const float* __restrict__ fc_W,
                                                    float* __restrict__ enc_Wt,
                                                    float* __restrict__ fc_Wt) {
    int idx = blockIdx.x * 256 + threadIdx.x;
    int stride = gridDim.x * 256;
    for (int i = idx; i < 4 * H * H; i += stride) {
        int l = i >> 18;
        int k = (i >> 9) & 511;
        int h = i & 511;
        fc_Wt[i] = fc_W[l * H * H + h * H + k];
    }
    for (int i = idx; i < OBS * H; i += stride) {
        int k = i >> 9;
        int h = i & 511;
        enc_Wt[i] = enc_W[h * OBS + k];
    }
}

// ---------------- persistent wavefront kernel ----------------
// spk planes: [producer 0..3][parity][512 h][256 n]  (transposed, f32 0/1)
__global__ __launch_bounds__(256) void snn_persistent(
    const float* __restrict__ x,       // [512][256][128]
    const float* __restrict__ mem0,    // [5][256][512]
    const float* __restrict__ enc_b,   // [512]
    const float* __restrict__ fc_b,    // [4][512]
    const float* __restrict__ enc_Wt,  // [128][512]
    const float* __restrict__ fc_Wt,   // [4][512][512] k-major
    float* __restrict__ spk,           // [4][2][512][256]
    int* __restrict__ slots,           // [256]
    float* __restrict__ out)           // [512][256][512] spikes + [5][256][512] mem
{
    const int tid = threadIdx.x;
    const int wg  = blockIdx.x;

    // fc tile: layer = wg/64; within plane: 8x8 tiles of 32n x 64h
    const int layer = wg >> 6;
    const int jt    = wg & 63;
    const int h0    = (jt & 7) << 6;
    const int n0    = (jt >> 3) << 5;
    const int i_n   = tid & 15;     // n-pair
    const int i_h   = tid >> 4;     // h-quad

    // enc tile: 8x32 tiles of 32n x 16h  (one per WG)
    const int en0 = (wg >> 5) << 5;
    const int eh0 = (wg & 31) << 4;

    __shared__ float Ssh[64][32];     // S^T chunk  (8 KB)
    __shared__ float Wsh[64][64];     // W^T chunk  (16 KB)
    __shared__ float Xsh[32][129];    // enc x tile, +1 pad (16.1 KB)
    __shared__ float EWsh[128][16];   // enc W^T    (8 KB)

    // persistent state in registers
    float mem_fc[2][4];
    float mem_enc[2];
    #pragma unroll
    for (int i = 0; i < 2; ++i)
        #pragma unroll
        for (int q = 0; q < 4; ++q)
            mem_fc[i][q] = mem0[(size_t)(layer + 1) * (NB * H) +
                                (size_t)(n0 + 2 * i_n + i) * H + h0 + 4 * i_h + q];
    #pragma unroll
    for (int r = 0; r < 2; ++r)
        mem_enc[r] = mem0[(size_t)(en0 + 2 * i_n + r) * H + eh0 + i_h];

    const float4 bfc = *(const float4*)(fc_b + layer * H + h0 + 4 * i_h);
    const float  benc = enc_b[eh0 + i_h];
    const float* Wl = fc_Wt + (size_t)layer * H * H;

    for (int p = 0; p < NPHASE; ++p) {
        const int  t_fc   = p - 1 - layer;
        const bool fc_act = (t_fc >= 0) && (t_fc < LSTEPS);
        const bool enc_act = (p < LSTEPS);

        float4 sA[2], wA[4];          // fc staging regs
        float4 ex[4], ew[2];          // enc staging regs
        const float* Sp = spk + (size_t)(layer * 2 + ((p - 1) & 1)) * (NB * H);

        // issue fc chunk-0 loads first, then enc loads (hide under fc compute)
        if (fc_act) {
            #pragma unroll
            for (int s = 0; s < 2; ++s) {
                int word = 4 * (tid + 256 * s);
                int r = word >> 5, c = word & 31;
                sA[s] = *(const float4*)(Sp + (size_t)r * NB + n0 + c);
            }
            #pragma unroll
            for (int s = 0; s < 4; ++s) {
                int word = 4 * (tid + 256 * s);
                int r = word >> 6, c = word & 63;
                wA[s] = *(const float4*)(Wl + (size_t)r * H + h0 + c);
            }
        }
        if (enc_act) {
            const float* xt = x + (size_t)p * NB * OBS;
            #pragma unroll
            for (int s = 0; s < 4; ++s) {
                int word = 4 * (tid + 256 * s);
                int r = word >> 7, c = word & 127;
                ex[s] = *(const float4*)(xt + (size_t)(en0 + r) * OBS + c);
            }
            #pragma unroll
            for (int s = 0; s < 2; ++s) {
                int word = 4 * (tid + 256 * s);
                int r = word >> 4, c = word & 15;
                ew[s] = *(const float4*)(enc_Wt + (size_t)r * H + eh0 + c);
            }
        }

        // ---------------- fc GEMM tile ----------------
        float acc[2][4] = {{0.f, 0.f, 0.f, 0.f}, {0.f, 0.f, 0.f, 0.f}};
        if (fc_act) {
            for (int cidx = 0; cidx < 8; ++cidx) {
                __syncthreads();                      // prev readers done
                #pragma unroll
                for (int s = 0; s < 2; ++s) {
                    int word = 4 * (tid + 256 * s);
                    *(float4*)(&Ssh[0][0] + word) = sA[s];
                }
                #pragma unroll
                for (int s = 0; s < 4; ++s) {
                    int word = 4 * (tid + 256 * s);
                    *(float4*)(&Wsh[0][0] + word) = wA[s];
                }
                __syncthreads();
                if (cidx < 7) {                       // prefetch next chunk
                    int kc = (cidx + 1) << 6;
                    #pragma unroll
                    for (int s = 0; s < 2; ++s) {
                        int word = 4 * (tid + 256 * s);
                        int r = word >> 5, c = word & 31;
                        sA[s] = *(const float4*)(Sp + (size_t)(kc + r) * NB + n0 + c);
                    }
                    #pragma unroll
                    for (int s = 0; s < 4; ++s) {
                        int word = 4 * (tid + 256 * s);
                        int r = word >> 6, c = word & 63;
                        wA[s] = *(const float4*)(Wl + (size_t)(kc + r) * H + h0 + c);
                    }
                }
                #pragma unroll 16
                for (int kk = 0; kk < 64; ++kk) {
                    float2 sv = *(const float2*)&Ssh[kk][2 * i_n];
                    float4 wv = *(const float4*)&Wsh[kk][4 * i_h];
                    acc[0][0] += sv.x * wv.x; acc[0][1] += sv.x * wv.y;
                    acc[0][2] += sv.x * wv.z; acc[0][3] += sv.x * wv.w;
                    acc[1][0] += sv.y * wv.x; acc[1][1] += sv.y * wv.y;
                    acc[1][2] += sv.y * wv.z; acc[1][3] += sv.y * wv.w;
                }
            }
            // LIF epilogue
            float* dst  = spk + (size_t)((layer + 1) * 2 + (p & 1)) * (NB * H);
            float* outp = out + (size_t)t_fc * (NB * H);
            float sp[2][4];
            #pragma unroll
            for (int i = 0; i < 2; ++i)
                #pragma unroll
                for (int q = 0; q < 4; ++q) {
                    float inp = acc[i][q] + ((const float*)&bfc)[q];
                    float mp  = mem_fc[i][q];
                    float reset = (mp > 1.0f) ? 1.0f : 0.0f;
                    float m = 0.9f * mp + inp - reset;
                    mem_fc[i][q] = m;
                    sp[i][q] = (m > 1.0f) ? 1.0f : 0.0f;
                }
            if (layer < 3) {
                #pragma unroll
                for (int q = 0; q < 4; ++q) {
                    float2 s2; s2.x = sp[0][q]; s2.y = sp[1][q];
                    *(float2*)(dst + (size_t)(h0 + 4 * i_h + q) * NB + n0 + 2 * i_n) = s2;
                }
            } else {
                #pragma unroll
                for (int i = 0; i < 2; ++i) {
                    float4 s4; s4.x = sp[i][0]; s4.y = sp[i][1]; s4.z = sp[i][2]; s4.w = sp[i][3];
                    *(float4*)(outp + (size_t)(n0 + 2 * i_n + i) * H + h0 + 4 * i_h) = s4;
                }
            }
        }

        // ---------------- encoder sliver ----------------
        if (enc_act) {
            if (!fc_act) __syncthreads();   // ensure prev-phase enc readers done
            else __syncthreads();           // fc compute done; safe to fill enc LDS
            // Xsh scalar stores (padded layout, float4 regs)
            #pragma unroll
            for (int s = 0; s < 4; ++s) {
                int word = 4 * (tid + 256 * s);
                int r = word >> 7, c = word & 127;
                float* q = &Xsh[r][c];
                q[0] = ex[s].x; q[1] = ex[s].y; q[2] = ex[s].z; q[3] = ex[s].w;
            }
            #pragma unroll
            for (int s = 0; s < 2; ++s) {
                int word = 4 * (tid + 256 * s);
                *(float4*)(&EWsh[0][0] + word) = ew[s];
            }
            __syncthreads();
            float ea0 = 0.f, ea1 = 0.f;
            #pragma unroll 8
            for (int kk = 0; kk < OBS; ++kk) {
                float w = EWsh[kk][i_h];
                ea0 += Xsh[2 * i_n][kk] * w;
                ea1 += Xsh[2 * i_n + 1][kk] * w;
            }
            float sp0, sp1;
            {
                float mp = mem_enc[0];
                float reset = (mp > 1.0f) ? 1.0f : 0.0f;
                float m = 0.9f * mp + (ea0 + benc) - reset;
                mem_enc[0] = m; sp0 = (m > 1.0f) ? 1.0f : 0.0f;
            }
            {
                float mp = mem_enc[1];
                float reset = (mp > 1.0f) ? 1.0f : 0.0f;
                float m = 0.9f * mp + (ea1 + benc) - reset;
                mem_enc[1] = m; sp1 = (m > 1.0f) ? 1.0f : 0.0f;
            }
            float2 s2; s2.x = sp0; s2.y = sp1;
            *(float2*)(spk + (size_t)(p & 1) * (NB * H) + (size_t)(eh0 + i_h) * NB + en0 + 2 * i_n) = s2;
        }

        // ---------------- grid barrier ----------------
        __syncthreads();
        __threadfence();
        if (tid == 0)
            __hip_atomic_store(slots + wg, p + 1, __ATOMIC_RELEASE, __HIP_MEMORY_SCOPE_AGENT);
        int ok;
        do {
            int v = __hip_atomic_load(slots + tid, __ATOMIC_ACQUIRE, __HIP_MEMORY_SCOPE_AGENT);
            ok = (v > p);
        } while (!__syncthreads_and(ok));
        __threadfence();
    }

    // final membrane state -> out tail [5][256][512]
    float* outm = out + (size_t)LSTEPS * NB * H;
    #pragma unroll
    for (int r = 0; r < 2; ++r)
        outm[(size_t)(en0 + 2 * i_n + r) * H + eh0 + i_h] = mem_enc[r];
    #pragma unroll
    for (int i = 0; i < 2; ++i) {
        float4 m4; m4.x = mem_fc[i][0]; m4.y = mem_fc[i][1]; m4.z = mem_fc[i][2]; m4.w = mem_fc[i][3];
        *(float4*)(outm + (size_t)(layer + 1) * (NB * H) +
                   (size_t)(n0 + 2 * i_n + i) * H + h0 + 4 * i_h) = m4;
    }
}

extern "C" void kernel_launch(void* const* d_in, const int* in_sizes, int n_in,
                              void* d_out, int out_size, void* d_ws, size_t ws_size,
                              hipStream_t stream) {
    const float* x     = (const float*)d_in[0];
    const float* mem0  = (const float*)d_in[1];
    const float* enc_W = (const float*)d_in[2];
    const float* enc_b = (const float*)d_in[3];
    const float* fc_W  = (const float*)d_in[4];
    const float* fc_b  = (const float*)d_in[5];
    float* out = (float*)d_out;

    float* fc_Wt  = (float*)d_ws;                    // 4*512*512
    float* enc_Wt = fc_Wt + 4 * H * H;               // 128*512
    float* spk    = enc_Wt + OBS * H;                // 4*2*512*256
    int*   slots  = (int*)(spk + 4 * 2 * NB * H);    // 256 ints

    hipMemsetAsync(slots, 0, NWG * sizeof(int), stream);
    prep_weights<<<dim3(512), dim3(256), 0, stream>>>(enc_W, fc_W, enc_Wt, fc_Wt);
    snn_persistent<<<dim3(NWG), dim3(256), 0, stream>>>(
        x, mem0, enc_b, fc_b, enc_Wt, fc_Wt, spk, slots, out);
}

// Round 3
// 11867.321 us; speedup vs baseline: 4.3982x; 3.8135x over previous
//
#include <hip/hip_runtime.h>

#define H 512
#define NB 256
#define OBS 128
#define LSTEPS 512
#define NPHASE (LSTEPS + 4)
#define NWG 256
#define PLANE (NB * H)     // f32 elems per mem plane
#define SPLANE (H * NB)    // spike plane elems (bf16), layout [h][n]

// fc_Wt[l][k][h] = fc_W[l][h][k];  enc_Wt[k][h] = enc_W[h][k]
__global__ __launch_bounds__(256) void prep_weights(const float* __restrict__ enc_W,
                                                    const float* __restrict__ fc_W,
                                                    float* __restrict__ enc_Wt,
                                                    float* __restrict__ fc_Wt) {
    int idx = blockIdx.x * 256 + threadIdx.x;
    int stride = gridDim.x * 256;
    for (int i = idx; i < 4 * H * H; i += stride) {
        int l = i >> 18;
        int k = (i >> 9) & 511;
        int h = i & 511;
        fc_Wt[i] = fc_W[l * H * H + h * H + k];
    }
    for (int i = idx; i < OBS * H; i += stride) {
        int k = i >> 9;
        int h = i & 511;
        enc_Wt[i] = enc_W[h * OBS + k];
    }
}

__device__ __forceinline__ unsigned short spike_bf16(float m) {
    return (m > 1.0f) ? (unsigned short)0x3F80 : (unsigned short)0;
}

// persistent wavefront: 256 WGs, 1/CU. fc WG: (layer, 64n x 32h). enc tile: 64n x 8h.
__global__ __launch_bounds__(256, 1) void snn_persistent(
    const float* __restrict__ x,        // [512][256][128]
    const float* __restrict__ mem0,     // [5][256][512]
    const float* __restrict__ enc_b,    // [512]
    const float* __restrict__ fc_b,     // [4][512]
    const float* __restrict__ enc_Wt,   // [128][512]
    const float* __restrict__ fc_Wt,    // [4][512][512] k-major
    unsigned short* __restrict__ spk,   // [4 src][2 parity][512 h][256 n] bf16
    int* __restrict__ slots,            // [256]
    float* __restrict__ out)            // [512][256][512] + [5][256][512]
{
    __shared__ float Wsh[512][32];    // 64 KB persistent fc weight slice
    __shared__ float Ssh[256][64];    // 64 KB spike chunk (f32)
    __shared__ float Xsh[64][65];     // 16.6 KB enc x chunk (padded)
    __shared__ float EWsh[128][8];    // 4 KB enc weight slice

    const int tid = threadIdx.x;
    const int wg  = blockIdx.x;

    const int layer = wg >> 6;
    const int jt = wg & 63;
    const int h0 = (jt & 15) << 5;    // 16 h-tiles of 32
    const int n0 = (jt >> 4) << 6;    // 4 n-tiles of 64
    const int i_h = tid & 15;         // h-pair
    const int i_n = tid >> 4;         // n-quad

    const int en0 = (wg & 3) << 6;
    const int eh0 = (wg >> 2) << 3;
    const int e_np = tid & 31;        // n-pair idx (0..31)
    const int e_h  = tid >> 5;        // 0..7

    // ---------- one-time staging ----------
    const float* Wl = fc_Wt + (size_t)layer * H * H;
    #pragma unroll
    for (int i = 0; i < 16; ++i) {
        int id = tid + 256 * i;            // float4 id, 4096 total
        int row = id >> 3, c4 = id & 7;
        float4 v = *(const float4*)(Wl + (size_t)row * H + h0 + 4 * c4);
        *(float4*)&Wsh[row][4 * c4] = v;
    }
    {
        int row = tid >> 1, seg = tid & 1;
        float4 v = *(const float4*)(enc_Wt + (size_t)row * H + eh0 + 4 * seg);
        *(float4*)&EWsh[row][4 * seg] = v;
    }

    const float2 bfc = *(const float2*)(fc_b + layer * H + h0 + 2 * i_h);
    const float benc = enc_b[eh0 + e_h];

    float mem_fc[4][2];
    #pragma unroll
    for (int i = 0; i < 4; ++i) {
        float2 m = *(const float2*)(mem0 + (size_t)(layer + 1) * PLANE +
                                    (size_t)(n0 + 4 * i_n + i) * H + h0 + 2 * i_h);
        mem_fc[i][0] = m.x; mem_fc[i][1] = m.y;
    }
    float mem_enc[2];
    #pragma unroll
    for (int r = 0; r < 2; ++r)
        mem_enc[r] = mem0[(size_t)(en0 + 2 * e_np + r) * H + eh0 + e_h];

    __syncthreads();

    // ---------- phase loop ----------
    for (int p = 0; p < NPHASE; ++p) {
        const int  t_fc   = p - 1 - layer;
        const bool fc_act = (t_fc >= 0) && (t_fc < LSTEPS);
        const bool enc_act = (p < LSTEPS);

        unsigned int sreg[32];
        float4 xreg[4];

        // spike source plane: producer src==layer, written last phase
        const unsigned short* Sp = spk + (size_t)(layer * 2 + ((p + 1) & 1)) * SPLANE;
        unsigned int* Spd = (unsigned int*)Sp;

        if (fc_act) {
            // issue chunk0 (k rows 0..255), relaxed agent atomics (sc0 sc1, no cache inv)
            #pragma unroll
            for (int i = 0; i < 32; ++i) {
                int d = tid + 256 * i;
                int row = d >> 5, col = d & 31;
                sreg[i] = __hip_atomic_load(Spd + (size_t)row * 128 + (n0 >> 1) + col,
                                            __ATOMIC_RELAXED, __HIP_MEMORY_SCOPE_AGENT);
            }
        }
        if (enc_act) {
            const float* xt = x + (size_t)p * NB * OBS;
            #pragma unroll
            for (int i = 0; i < 4; ++i) {
                int id = tid + 256 * i;
                int row = id >> 4, c4 = id & 15;
                xreg[i] = *(const float4*)(xt + (size_t)(en0 + row) * OBS + 4 * c4);
            }
        }

        // ---------------- fc GEMM (64n x 32h, K=512 in 2 chunks) ----------------
        float acc[4][2] = {{0.f,0.f},{0.f,0.f},{0.f,0.f},{0.f,0.f}};
        if (fc_act) {
            for (int c = 0; c < 2; ++c) {
                __syncthreads();                       // prev readers of Ssh done
                #pragma unroll
                for (int i = 0; i < 32; ++i) {
                    int d = tid + 256 * i;
                    int row = d >> 5, col = d & 31;
                    unsigned int u = sreg[i];
                    float lo = __uint_as_float(u << 16);
                    float hi = __uint_as_float(u & 0xFFFF0000u);
                    *(float2*)&Ssh[row][2 * col] = make_float2(lo, hi);
                }
                __syncthreads();
                if (c == 0) {                          // prefetch chunk1 (k 256..511)
                    #pragma unroll
                    for (int i = 0; i < 32; ++i) {
                        int d = tid + 256 * i;
                        int row = 256 + (d >> 5), col = d & 31;
                        sreg[i] = __hip_atomic_load(Spd + (size_t)row * 128 + (n0 >> 1) + col,
                                                    __ATOMIC_RELAXED, __HIP_MEMORY_SCOPE_AGENT);
                    }
                }
                const int kbase = c << 8;
                #pragma unroll 8
                for (int kk = 0; kk < 256; ++kk) {
                    float4 sv = *(const float4*)&Ssh[kk][4 * i_n];
                    float2 wv = *(const float2*)&Wsh[kbase + kk][2 * i_h];
                    acc[0][0] += sv.x * wv.x; acc[0][1] += sv.x * wv.y;
                    acc[1][0] += sv.y * wv.x; acc[1][1] += sv.y * wv.y;
                    acc[2][0] += sv.z * wv.x; acc[2][1] += sv.z * wv.y;
                    acc[3][0] += sv.w * wv.x; acc[3][1] += sv.w * wv.y;
                }
            }
            // LIF epilogue
            float sp[4][2];
            #pragma unroll
            for (int i = 0; i < 4; ++i) {
                #pragma unroll
                for (int j = 0; j < 2; ++j) {
                    float inp = acc[i][j] + ((j == 0) ? bfc.x : bfc.y);
                    float mp  = mem_fc[i][j];
                    float reset = (mp > 1.0f) ? 1.0f : 0.0f;
                    float m = 0.9f * mp + inp - reset;
                    mem_fc[i][j] = m;
                    sp[i][j] = m;
                }
            }
            if (layer < 3) {
                unsigned short* dst = spk + (size_t)((layer + 1) * 2 + (p & 1)) * SPLANE;
                #pragma unroll
                for (int j = 0; j < 2; ++j) {
                    int h = h0 + 2 * i_h + j;
                    unsigned long long wq =
                        (unsigned long long)spike_bf16(sp[0][j])
                      | ((unsigned long long)spike_bf16(sp[1][j]) << 16)
                      | ((unsigned long long)spike_bf16(sp[2][j]) << 32)
                      | ((unsigned long long)spike_bf16(sp[3][j]) << 48);
                    __hip_atomic_store((unsigned long long*)(dst + (size_t)h * NB + n0 + 4 * i_n),
                                       wq, __ATOMIC_RELAXED, __HIP_MEMORY_SCOPE_AGENT);
                }
            } else {
                float* outp = out + (size_t)t_fc * PLANE;
                #pragma unroll
                for (int i = 0; i < 4; ++i) {
                    float2 s2;
                    s2.x = (sp[i][0] > 1.0f) ? 1.0f : 0.0f;
                    s2.y = (sp[i][1] > 1.0f) ? 1.0f : 0.0f;
                    *(float2*)(outp + (size_t)(n0 + 4 * i_n + i) * H + h0 + 2 * i_h) = s2;
                }
            }
        }

        // ---------------- encoder sliver (64n x 8h, K=128 in 2 chunks) ----------------
        if (enc_act) {
            float ea0 = 0.f, ea1 = 0.f;
            for (int ec = 0; ec < 2; ++ec) {
                __syncthreads();                       // prev readers of Xsh done
                #pragma unroll
                for (int i = 0; i < 4; ++i) {
                    int id = tid + 256 * i;
                    int row = id >> 4, c4 = id & 15;
                    *(float4*)&Xsh[row][4 * c4] = xreg[i];
                }
                __syncthreads();
                if (ec == 0) {                         // prefetch k 64..127
                    const float* xt = x + (size_t)p * NB * OBS;
                    #pragma unroll
                    for (int i = 0; i < 4; ++i) {
                        int id = tid + 256 * i;
                        int row = id >> 4, c4 = id & 15;
                        xreg[i] = *(const float4*)(xt + (size_t)(en0 + row) * OBS + 64 + 4 * c4);
                    }
                }
                const int kb = ec << 6;
                #pragma unroll 8
                for (int kk = 0; kk < 64; ++kk) {
                    float wv = EWsh[kb + kk][e_h];
                    ea0 += Xsh[2 * e_np + 0][kk] * wv;
                    ea1 += Xsh[2 * e_np + 1][kk] * wv;
                }
            }
            float sp0, sp1;
            {
                float mp = mem_enc[0];
                float reset = (mp > 1.0f) ? 1.0f : 0.0f;
                float m = 0.9f * mp + (ea0 + benc) - reset;
                mem_enc[0] = m; sp0 = m;
            }
            {
                float mp = mem_enc[1];
                float reset = (mp > 1.0f) ? 1.0f : 0.0f;
                float m = 0.9f * mp + (ea1 + benc) - reset;
                mem_enc[1] = m; sp1 = m;
            }
            unsigned short* dst = spk + (size_t)(p & 1) * SPLANE;   // src 0
            unsigned int wd = (unsigned int)spike_bf16(sp0)
                            | ((unsigned int)spike_bf16(sp1) << 16);
            int n = en0 + 2 * e_np;
            __hip_atomic_store((unsigned int*)(dst + (size_t)(eh0 + e_h) * NB + n),
                               wd, __ATOMIC_RELAXED, __HIP_MEMORY_SCOPE_AGENT);
        }

        // ---------------- grid barrier (no cache-invalidating ops) ----------------
        asm volatile("s_waitcnt vmcnt(0)" ::: "memory");  // own sc1 stores at L3
        __syncthreads();                                  // all threads' stores drained
        if (tid == 0)
            __hip_atomic_store(slots + wg, p + 1, __ATOMIC_RELAXED, __HIP_MEMORY_SCOPE_AGENT);
        int ok;
        do {
            int v = __hip_atomic_load(slots + tid, __ATOMIC_RELAXED, __HIP_MEMORY_SCOPE_AGENT);
            ok = (v > p);
        } while (!__syncthreads_and(ok));
        asm volatile("" ::: "memory");
    }

    // ---------- final membrane state ----------
    float* outm = out + (size_t)LSTEPS * PLANE;
    #pragma unroll
    for (int r = 0; r < 2; ++r)
        outm[(size_t)(en0 + 2 * e_np + r) * H + eh0 + e_h] = mem_enc[r];
    #pragma unroll
    for (int i = 0; i < 4; ++i) {
        float2 m2; m2.x = mem_fc[i][0]; m2.y = mem_fc[i][1];
        *(float2*)(outm + (size_t)(layer + 1) * PLANE +
                   (size_t)(n0 + 4 * i_n + i) * H + h0 + 2 * i_h) = m2;
    }
}

extern "C" void kernel_launch(void* const* d_in, const int* in_sizes, int n_in,
                              void* d_out, int out_size, void* d_ws, size_t ws_size,
                              hipStream_t stream) {
    const float* x     = (const float*)d_in[0];
    const float* mem0  = (const float*)d_in[1];
    const float* enc_W = (const float*)d_in[2];
    const float* enc_b = (const float*)d_in[3];
    const float* fc_W  = (const float*)d_in[4];
    const float* fc_b  = (const float*)d_in[5];
    float* out = (float*)d_out;

    float* fc_Wt  = (float*)d_ws;                         // 4*512*512 f32
    float* enc_Wt = fc_Wt + 4 * H * H;                    // 128*512 f32
    unsigned short* spk = (unsigned short*)(enc_Wt + OBS * H);  // 8 planes bf16
    int* slots = (int*)(spk + 8 * (size_t)SPLANE);        // 256 ints

    hipMemsetAsync(slots, 0, NWG * sizeof(int), stream);
    prep_weights<<<dim3(512), dim3(256), 0, stream>>>(enc_W, fc_W, enc_Wt, fc_Wt);
    snn_persistent<<<dim3(NWG), dim3(256), 0, stream>>>(
        x, mem0, enc_b, fc_b, enc_Wt, fc_Wt, spk, slots, out);
}